// Round 8
// baseline (196.959 us; speedup 1.0000x reference)
//
#include <hip/hip_runtime.h>

#define BB 16
#define NN 512
#define DD 256
#define HH 8
#define CC 16

typedef unsigned short u16;
using short8 = __attribute__((ext_vector_type(8))) short;
using f32x4  = __attribute__((ext_vector_type(4))) float;

__device__ __forceinline__ float gelu_f(float x) {
    return 0.5f * x * (1.0f + erff(x * 0.70710678118654752f));
}
__device__ __forceinline__ u16 f2bf(float f) {
    unsigned int u = __float_as_uint(f);
    unsigned int r = u + 0x7FFFu + ((u >> 16) & 1u);
    return (u16)(r >> 16);
}
// packed f32x2 -> bf16x2 (RTNE, bit-identical to f2bf), 1 instr vs ~8
__device__ __forceinline__ unsigned cvtpk(float lo, float hi) {
    unsigned r;
    asm("v_cvt_pk_bf16_f32 %0, %1, %2" : "=v"(r) : "v"(lo), "v"(hi));
    return r;
}
// async global->LDS, 16B/lane; LDS dest = wave-uniform base + lane*16
__device__ __forceinline__ void gld16(const u16* g, const u16* l) {
    __builtin_amdgcn_global_load_lds(
        (const __attribute__((address_space(1))) unsigned int*)g,
        (__attribute__((address_space(3))) unsigned int*)l, 16, 0, 0);
}

// Q pre-scale: (1/sqrt(32)) * log2(e)  -> attention uses exp2
#define QSCALE 0.25505412f

// latency-unrolled matvec: 8 independent accumulator chains
__device__ __forceinline__ float mv256(const float* __restrict__ a,
                                       const float* __restrict__ W, int d)
{
    float acc[8] = {0.f, 0.f, 0.f, 0.f, 0.f, 0.f, 0.f, 0.f};
    for (int k = 0; k < 256; k += 8) {
#pragma unroll
        for (int j = 0; j < 8; ++j)
            acc[j] += a[k + j] * W[(size_t)(k + j) * 256 + d];
    }
    return ((acc[0] + acc[1]) + (acc[2] + acc[3])) + ((acc[4] + acc[5]) + (acc[6] + acc[7]));
}

// ---------------------------------------------------------------------------
// Generic 64x64-tile bf16 MFMA GEMM (BK=32, LDS staging). grid (128, 4).
// O = act(A @ Wt + bias + tvec[b]); token-major bf16 or fp32 out.
// CS=1: additionally reduce the fp32 tile per class and atomicAdd into gsum.
// ---------------------------------------------------------------------------
template<int ACT, int HAS_B, int HAS_T, int OUT_F32, int CS>
__global__ __launch_bounds__(256) void gemm64(
    const u16* __restrict__ A, const u16* __restrict__ W,
    u16* __restrict__ O, float* __restrict__ OF,
    const float* __restrict__ bias, const float* __restrict__ tvec,
    const int* __restrict__ labels, float* __restrict__ gsum)
{
    __shared__ __align__(16) u16 As[64 * 32];
    __shared__ __align__(16) u16 Bs[64 * 32];
    const int tid = threadIdx.x, wave = tid >> 6, lane = tid & 63;
    const int col = lane & 15, quad = lane >> 4;
    const int mbase = blockIdx.x * 64;
    const int nbase = blockIdx.y * 64;
    const int srow = lane >> 2, skk = (lane & 3) * 8;
    const int mh = (wave & 1) * 32, nh = (wave >> 1) * 32;

    f32x4 acc[2][2];
#pragma unroll
    for (int i = 0; i < 2; ++i)
#pragma unroll
        for (int j = 0; j < 2; ++j) acc[i][j] = (f32x4){0.f, 0.f, 0.f, 0.f};

    for (int k0 = 0; k0 < DD; k0 += 32) {
        gld16(A + (size_t)(mbase + wave * 16 + srow) * DD + k0 + skk, &As[wave * 512]);
        gld16(W + (size_t)(nbase + wave * 16 + srow) * DD + k0 + skk, &Bs[wave * 512]);
        __syncthreads();
        short8 af[2], bfr[2];
#pragma unroll
        for (int i = 0; i < 2; ++i) af[i]  = *(const short8*)&As[(mh + i * 16 + col) * 32 + quad * 8];
#pragma unroll
        for (int j = 0; j < 2; ++j) bfr[j] = *(const short8*)&Bs[(nh + j * 16 + col) * 32 + quad * 8];
#pragma unroll
        for (int i = 0; i < 2; ++i)
#pragma unroll
            for (int j = 0; j < 2; ++j)
                acc[i][j] = __builtin_amdgcn_mfma_f32_16x16x32_bf16(af[i], bfr[j], acc[i][j], 0, 0, 0);
        __syncthreads();
    }

    const int b = mbase >> 9;
    if constexpr (!CS) {
#pragma unroll
        for (int i = 0; i < 2; ++i) {
#pragma unroll
            for (int j = 0; j < 2; ++j) {
                const int ccol = nbase + nh + j * 16 + col;
                float vv[4];
#pragma unroll
                for (int r = 0; r < 4; ++r) {
                    float v = acc[i][j][r];
                    if (HAS_B) v += bias[ccol];
                    if (HAS_T) v += tvec[b * DD + ccol];
                    if (ACT)   v = gelu_f(v);
                    vv[r] = v;
                }
                const int crow0 = mbase + mh + i * 16 + quad * 4;
                if (OUT_F32) {
#pragma unroll
                    for (int r = 0; r < 4; ++r) OF[(size_t)(crow0 + r) * DD + ccol] = vv[r];
                } else {
                    const unsigned a = cvtpk(vv[0], vv[1]), c = cvtpk(vv[2], vv[3]);
                    O[(size_t)(crow0 + 0) * DD + ccol] = (u16)a;
                    O[(size_t)(crow0 + 1) * DD + ccol] = (u16)(a >> 16);
                    O[(size_t)(crow0 + 2) * DD + ccol] = (u16)c;
                    O[(size_t)(crow0 + 3) * DD + ccol] = (u16)(c >> 16);
                }
            }
        }
    } else {
        // fused classsum epilogue: write F + stage tile in LDS, per-class
        // reduce in-block, atomicAdd into gsum[b][c][d].
        __shared__ float Fs[64][65];
        __shared__ float gs[4][CC][64];
        __shared__ int lab2[64];
        if (tid < 64) lab2[tid] = labels[mbase + tid];
#pragma unroll
        for (int i = 0; i < 2; ++i) {
#pragma unroll
            for (int j = 0; j < 2; ++j) {
                const int lcol = nh + j * 16 + col;
                const int ccol = nbase + lcol;
#pragma unroll
                for (int r = 0; r < 4; ++r) {
                    const int lrow = mh + i * 16 + quad * 4 + r;
                    float v = acc[i][j][r];
                    if (HAS_B) v += bias[ccol];
                    if (HAS_T) v += tvec[b * DD + ccol];
                    if (ACT)   v = gelu_f(v);
                    OF[(size_t)(mbase + lrow) * DD + ccol] = v;
                    Fs[lrow][lcol] = v;
                }
            }
        }
        __syncthreads();
        float a[CC];
#pragma unroll
        for (int c = 0; c < CC; ++c) a[c] = 0.f;
#pragma unroll
        for (int n = 0; n < 16; ++n) {
            const float v = Fs[wave * 16 + n][lane];
            const int lb = lab2[wave * 16 + n];
#pragma unroll
            for (int c = 0; c < CC; ++c) a[c] += (lb == c) ? v : 0.f;
        }
#pragma unroll
        for (int c = 0; c < CC; ++c) gs[wave][c][lane] = a[c];
        __syncthreads();
#pragma unroll
        for (int i = 0; i < 4; ++i) {
            const int c = wave * 4 + i;
            atomicAdd(&gsum[((size_t)b * CC + c) * DD + nbase + lane],
                      gs[0][c][lane] + gs[1][c][lane] + gs[2][c][lane] + gs[3][c][lane]);
        }
    }
}

// ---------------------------------------------------------------------------
// QKV GEMM, sel-merged (R8): grid (128, 4), 768 threads = 12 waves.
// wave = sel*4 + quadrant; A-tile staged ONCE per block (was 3x across
// sel-split blocks), plus 3 B-tiles. Per-wave compute/epilogue identical to
// the old per-sel kernel. Q,K head-major [b,h,n,32] (Q scaled), V [b,h,32,n].
// ---------------------------------------------------------------------------
__global__ __launch_bounds__(768) void gemm_qkv(
    const u16* __restrict__ A,
    const u16* __restrict__ W0, const u16* __restrict__ W1, const u16* __restrict__ W2,
    u16* __restrict__ O0, u16* __restrict__ O1, u16* __restrict__ O2)
{
    __shared__ __align__(16) u16 As[64 * 32];
    __shared__ __align__(16) u16 Bs[3][64 * 32];
    const int tid = threadIdx.x, wave = tid >> 6, lane = tid & 63;
    const int col = lane & 15, quad = lane >> 4;
    const int sel = wave >> 2, wq = wave & 3;
    const int mbase = blockIdx.x * 64;
    const int nbase = blockIdx.y * 64;
    const u16* W = (sel == 0) ? W0 : ((sel == 1) ? W1 : W2);
    u16* O = (sel == 0) ? O0 : ((sel == 1) ? O1 : O2);
    const int srow = lane >> 2, skk = (lane & 3) * 8;
    const int mh = (wq & 1) * 32, nh = (wq >> 1) * 32;

    f32x4 acc[2][2];
#pragma unroll
    for (int i = 0; i < 2; ++i)
#pragma unroll
        for (int j = 0; j < 2; ++j) acc[i][j] = (f32x4){0.f, 0.f, 0.f, 0.f};

    for (int k0 = 0; k0 < DD; k0 += 32) {
        gld16(W + (size_t)(nbase + wq * 16 + srow) * DD + k0 + skk, &Bs[sel][wq * 512]);
        if (wave < 4)
            gld16(A + (size_t)(mbase + wq * 16 + srow) * DD + k0 + skk, &As[wq * 512]);
        __syncthreads();
        short8 af[2], bfr[2];
#pragma unroll
        for (int i = 0; i < 2; ++i) af[i]  = *(const short8*)&As[(mh + i * 16 + col) * 32 + quad * 8];
#pragma unroll
        for (int j = 0; j < 2; ++j) bfr[j] = *(const short8*)&Bs[sel][(nh + j * 16 + col) * 32 + quad * 8];
#pragma unroll
        for (int i = 0; i < 2; ++i)
#pragma unroll
            for (int j = 0; j < 2; ++j)
                acc[i][j] = __builtin_amdgcn_mfma_f32_16x16x32_bf16(af[i], bfr[j], acc[i][j], 0, 0, 0);
        __syncthreads();
    }

    const int b = mbase >> 9;
#pragma unroll
    for (int i = 0; i < 2; ++i) {
#pragma unroll
        for (int j = 0; j < 2; ++j) {
            const int ccol = nbase + nh + j * 16 + col;
            const int tok0 = (mbase & 511) + mh + i * 16 + quad * 4;
            const int head = ccol >> 5, dk = ccol & 31;
            if (sel == 2) {
                uint2 pk;
                pk.x = cvtpk(acc[i][j][0], acc[i][j][1]);
                pk.y = cvtpk(acc[i][j][2], acc[i][j][3]);
                *(uint2*)&O[(((size_t)b * HH + head) * 32 + dk) * NN + tok0] = pk;
            } else {
                float vv[4];
#pragma unroll
                for (int r = 0; r < 4; ++r) {
                    float v = acc[i][j][r];
                    if (sel == 0) v *= QSCALE;
                    vv[r] = v;
                }
                const unsigned a = cvtpk(vv[0], vv[1]), c = cvtpk(vv[2], vv[3]);
                const size_t base = ((size_t)b * HH + head) * NN;
                O[(base + tok0 + 0) * 32 + dk] = (u16)a;
                O[(base + tok0 + 1) * 32 + dk] = (u16)(a >> 16);
                O[(base + tok0 + 2) * 32 + dk] = (u16)c;
                O[(base + tok0 + 3) * 32 + dk] = (u16)(c >> 16);
            }
        }
    }
}

// ---------------------------------------------------------------------------
// Flash MFMA attention, no-max softmax (pre-scaled by log2e/sqrt(dk), exp2).
// R8: 256 q-rows per block (16 waves, grid 256) — V staged 2x per (b,h)
// (was 4x), per-block fixed costs halve. Per-wave main loop unchanged
// (R2 structure + cvtpk + setprio). LDS ~52KB, 1 blk/CU x 16 waves.
// grid 256: gid = qb*128 + (b*8+h); COLSUM partial is [128 bh][2 qb][32].
// ---------------------------------------------------------------------------
template<int COLSUM>
__global__ __launch_bounds__(1024) void attn_mfma(
    const u16* __restrict__ Qh, const u16* __restrict__ Kh,
    const u16* __restrict__ VT, u16* __restrict__ O,
    float* __restrict__ partial)
{
    __shared__ __align__(16) u16 Vt[32 * 520];
    __shared__ __align__(16) u16 Pc[16][16 * 32];
    __shared__ float cs[16][32];
    const int tid = threadIdx.x, wave = tid >> 6, lane = tid & 63;
    const int col = lane & 15, quad = lane >> 4;
    const int gid = blockIdx.x;
    const int qb = gid >> 7, bh = gid & 127;
    const int q0 = qb * 256 + wave * 16;

    const u16* vsrc = VT + (size_t)bh * 32 * NN;
#pragma unroll
    for (int i = 0; i < 2; ++i) {
        const int row = wave + i * 16;
        gld16(vsrc + (size_t)row * NN + lane * 8, &Vt[row * 520]);
    }
    const short8 aq = *(const short8*)(Qh + ((size_t)bh * NN + q0 + col) * 32 + quad * 8);
    __syncthreads();

    const u16* ksrc = Kh + (size_t)bh * NN * 32;
    float l[4] = {0.f, 0.f, 0.f, 0.f};
    f32x4 oacc[2];
    oacc[0] = (f32x4){0.f, 0.f, 0.f, 0.f};
    oacc[1] = (f32x4){0.f, 0.f, 0.f, 0.f};

    // K prefetch: two fragments in flight one g-iteration ahead
    short8 bkp[2];
#pragma unroll
    for (int k2 = 0; k2 < 2; ++k2)
        bkp[k2] = *(const short8*)(ksrc + (size_t)(k2 * 16 + col) * 32 + quad * 8);

    for (int g = 0; g < 16; ++g) {
        short8 bk0 = bkp[0], bk1 = bkp[1];
        if (g < 15) {
#pragma unroll
            for (int k2 = 0; k2 < 2; ++k2)
                bkp[k2] = *(const short8*)(ksrc + (size_t)((g * 2 + 2 + k2) * 16 + col) * 32 + quad * 8);
        }
        const f32x4 z = {0.f, 0.f, 0.f, 0.f};
        __builtin_amdgcn_s_setprio(1);
        const f32x4 s0 = __builtin_amdgcn_mfma_f32_16x16x32_bf16(aq, bk0, z, 0, 0, 0);
        const f32x4 s1 = __builtin_amdgcn_mfma_f32_16x16x32_bf16(aq, bk1, z, 0, 0, 0);
        __builtin_amdgcn_s_setprio(0);
#pragma unroll
        for (int k2 = 0; k2 < 2; ++k2) {
            const f32x4 s = k2 ? s1 : s0;
            const float p0 = exp2f(s[0]), p1 = exp2f(s[1]);
            const float p2 = exp2f(s[2]), p3 = exp2f(s[3]);
            l[0] += p0; l[1] += p1; l[2] += p2; l[3] += p3;
            const unsigned pa = cvtpk(p0, p1), pb = cvtpk(p2, p3);
            // swizzled unit index: u = k2*2 + (col>>3), u' = u ^ quad
            const int ubase = (((k2 * 2 + (col >> 3)) ^ quad) << 3) + (col & 7);
            u16* pcb = &Pc[wave][0];
            pcb[(quad * 4 + 0) * 32 + ubase] = (u16)pa;
            pcb[(quad * 4 + 1) * 32 + ubase] = (u16)(pa >> 16);
            pcb[(quad * 4 + 2) * 32 + ubase] = (u16)pb;
            pcb[(quad * 4 + 3) * 32 + ubase] = (u16)(pb >> 16);
        }
        const short8 ap = *(const short8*)&Pc[wave][col * 32 + ((quad ^ (col >> 2)) << 3)];
        __builtin_amdgcn_s_setprio(1);
#pragma unroll
        for (int nt = 0; nt < 2; ++nt) {
            const short8 bv = *(const short8*)&Vt[(nt * 16 + col) * 520 + g * 32 + quad * 8];
            oacc[nt] = __builtin_amdgcn_mfma_f32_16x16x32_bf16(ap, bv, oacc[nt], 0, 0, 0);
        }
        __builtin_amdgcn_s_setprio(0);
    }
#pragma unroll
    for (int r = 0; r < 4; ++r) {
        l[r] += __shfl_xor(l[r], 1, 64);
        l[r] += __shfl_xor(l[r], 2, 64);
        l[r] += __shfl_xor(l[r], 4, 64);
        l[r] += __shfl_xor(l[r], 8, 64);
    }
    float invl[4];
#pragma unroll
    for (int r = 0; r < 4; ++r) invl[r] = 1.0f / l[r];
    if (COLSUM) {
        float sv[2] = {0.f, 0.f};
#pragma unroll
        for (int nt = 0; nt < 2; ++nt) {
#pragma unroll
            for (int r = 0; r < 4; ++r) sv[nt] += oacc[nt][r] * invl[r];
            sv[nt] += __shfl_xor(sv[nt], 16, 64);
            sv[nt] += __shfl_xor(sv[nt], 32, 64);
        }
        if (lane < 16) { cs[wave][col] = sv[0]; cs[wave][16 + col] = sv[1]; }
        __syncthreads();
        if (tid < 32) {
            float t = 0.f;
#pragma unroll
            for (int w = 0; w < 16; ++w) t += cs[w][tid];
            partial[(size_t)(bh * 2 + qb) * 32 + tid] = t;
        }
    } else {
        const int b = bh >> 3, h = bh & 7;
        u16* obase = O + ((size_t)b * NN) * DD + h * 32;
#pragma unroll
        for (int nt = 0; nt < 2; ++nt) {
            const unsigned a = cvtpk(oacc[nt][0] * invl[0], oacc[nt][1] * invl[1]);
            const unsigned c = cvtpk(oacc[nt][2] * invl[2], oacc[nt][3] * invl[3]);
            const size_t rb = (size_t)(q0 + quad * 4);
            obase[(rb + 0) * DD + nt * 16 + col] = (u16)a;
            obase[(rb + 1) * DD + nt * 16 + col] = (u16)(a >> 16);
            obase[(rb + 2) * DD + nt * 16 + col] = (u16)c;
            obase[(rb + 3) * DD + nt * 16 + col] = (u16)(c >> 16);
        }
    }
}

// ---------------------------------------------------------------------------
// convert + weight transposes + zero gsum + stage aggr's fp32 weights into
// the workspace (guards against cold-HBM outliers on aggr's weight reads).
// ---------------------------------------------------------------------------
__global__ __launch_bounds__(256) void convert_all(
    const float* __restrict__ e, u16* __restrict__ E, u16* __restrict__ G,
    const float* s0, const float* s1, const float* s2, const float* s3,
    const float* s4, const float* s5, const float* s6, const float* s7,
    const float* s8, u16* __restrict__ Wt, float* __restrict__ gsum,
    const float* __restrict__ c0, const float* __restrict__ c1,
    const float* __restrict__ c2, float* __restrict__ wc)
{
    const int bx = blockIdx.x;
    if (bx < 2048) {
        const size_t i = ((size_t)bx * 256 + threadIdx.x) * 4;
        const float4 v = *(const float4*)(e + i);
        uint2 ev, gv;
        ev.x = cvtpk(v.x, v.y); ev.y = cvtpk(v.z, v.w);
        gv.x = cvtpk(gelu_f(v.x), gelu_f(v.y));
        gv.y = cvtpk(gelu_f(v.z), gelu_f(v.w));
        *(uint2*)(E + i) = ev;
        *(uint2*)(G + i) = gv;
    } else if (bx < 2192) {
        const int w = bx - 2048;
        const int my = w >> 4, kb = (w & 15) * 16;
        const int n = threadIdx.x;
        const float* S;
        switch (my) {
            case 0: S = s0; break; case 1: S = s1; break; case 2: S = s2; break;
            case 3: S = s3; break; case 4: S = s4; break; case 5: S = s5; break;
            case 6: S = s6; break; case 7: S = s7; break; default: S = s8; break;
        }
        u16* Dst = Wt + (size_t)my * 65536;
        for (int r = 0; r < 16; ++r) {
            const int k = kb + r;
            Dst[(size_t)n * 256 + k] = f2bf(S[(size_t)k * 256 + n]);
        }
    } else if (bx < 2256) {
        const int z = bx - 2192;   // 64 blocks zero gsum (65536 floats)
        const float4 zz = {0.f, 0.f, 0.f, 0.f};
        *(float4*)(gsum + (size_t)z * 1024 + threadIdx.x * 4) = zz;
    } else {
        // 192 blocks: bit-exact fp32 copy of Wo1 / resW / ffW1-top (256KB each)
        const int w = bx - 2256;
        const int m = w >> 6;              // 0..2
        const float* src = (m == 0) ? c0 : ((m == 1) ? c1 : c2);
        const size_t off = (size_t)(w & 63) * 1024 + threadIdx.x * 4;
        *(float4*)(wc + (size_t)m * 65536 + off) = *(const float4*)(src + off);
    }
}

// aggr: m1=mean(attn1 colsums); a1=gelu(m1@Wo1); a2=gelu(a1@resW+resb);
// tvec=a2@ffW1[0:256]; also counts histogram. grid BB.
// partial is [128 bh][2 qb][32] (R8: 256-q attn blocks).
__global__ __launch_bounds__(256) void aggr_v2(
    const float* __restrict__ partial, const float* __restrict__ Wo1f,
    const float* __restrict__ resW, const float* __restrict__ resb,
    const float* __restrict__ W1, const int* __restrict__ labels,
    float* __restrict__ tvec, float* __restrict__ counts)
{
    const int b = blockIdx.x, d = threadIdx.x;
    __shared__ float a0[256], a1[256], a2[256];
    __shared__ int hist[CC];
    if (d < CC) hist[d] = 0;
    const int h = d >> 5, d32 = d & 31;
    float s = 0.f;
#pragma unroll
    for (int qb = 0; qb < 2; ++qb)
        s += partial[(size_t)(((b * 8 + h) * 2) + qb) * 32 + d32];
    a0[d] = s * (1.0f / NN);
    __syncthreads();
    atomicAdd(&hist[labels[b * NN + d]], 1);
    atomicAdd(&hist[labels[b * NN + 256 + d]], 1);
    a1[d] = gelu_f(mv256(a0, Wo1f, d));
    __syncthreads();
    a2[d] = gelu_f(mv256(a1, resW, d) + resb[d]);
    __syncthreads();
    tvec[b * 256 + d] = mv256(a2, W1, d);
    if (d < CC) counts[b * CC + d] = (float)hist[d];
}

__global__ __launch_bounds__(256) void out_kernel(
    const float* __restrict__ F, const int* __restrict__ labels,
    const float* __restrict__ g, const float* __restrict__ counts,
    float* __restrict__ out)
{
    const int b = blockIdx.y;
    const int wave = threadIdx.x >> 6, lane = threadIdx.x & 63;
    const int n = blockIdx.x * 4 + wave;
    const float* fn = F + ((size_t)b * NN + n) * DD;
    const float* gb = g + (size_t)b * CC * DD;
    float fv[4];
#pragma unroll
    for (int i = 0; i < 4; ++i) fv[i] = fn[lane * 4 + i];
    float selfdot = 0.f;
#pragma unroll
    for (int i = 0; i < 4; ++i) selfdot += fv[i] * fv[i];
    float accs[CC];
#pragma unroll
    for (int c = 0; c < CC; ++c) {
        float sacc = 0.f;
#pragma unroll
        for (int i = 0; i < 4; ++i) sacc += fv[i] * gb[c * DD + lane * 4 + i];
        accs[c] = sacc;
    }
    for (int off = 32; off; off >>= 1) {
        selfdot += __shfl_xor(selfdot, off, 64);
#pragma unroll
        for (int c = 0; c < CC; ++c) accs[c] += __shfl_xor(accs[c], off, 64);
    }
    if (lane < CC) {
        const int c = lane;
        const int same = (labels[b * NN + n] == c) ? 1 : 0;
        const float num = accs[c] - (same ? selfdot : 0.f);
        const float den = counts[b * CC + c] - (float)same;
        out[((size_t)b * NN + n) * CC + c] = num / den;
    }
}

// ---------------------------------------------------------------------------
extern "C" void kernel_launch(void* const* d_in, const int* in_sizes, int n_in,
                              void* d_out, int out_size, void* d_ws, size_t ws_size,
                              hipStream_t stream)
{
    const float* emb    = (const float*)d_in[0];
    const int*   labels = (const int*)  d_in[1];
    const float* Wo1f = (const float*)d_in[9];
    const float* resW = (const float*)d_in[10];
    const float* resb = (const float*)d_in[11];
    const float* ffW1 = (const float*)d_in[12];
    const float* ffb1 = (const float*)d_in[13];
    const float* ffb2 = (const float*)d_in[15];
    float* out = (float*)d_out;

    const size_t SBE = (size_t)BB * NN * DD;
    u16* BUF0 = (u16*)d_ws;          // E_bf, later X1
    u16* BUF1 = BUF0 + SBE;          // gelu(emb) bf16
    u16* BUF2 = BUF1 + SBE;          // Qh [b,h,n,32]
    u16* BUF3 = BUF2 + SBE;          // Kh, later H
    u16* BUF4 = BUF3 + SBE;          // VT [b,h,32,n]
    u16* BUF5 = BUF4 + SBE;          // attn0 out (token-major)
    u16* Wt   = BUF5 + SBE;          // 9 x [256n x 256k] bf16 transposed
    float* F      = (float*)(Wt + 9 * 65536);   // [8192x256] fp32 features
    float* tvec   = F + SBE;
    float* partial= tvec + BB * 256;            // [128 bh][2 qb][32]
    float* gsum   = partial + 128 * 8 * 32;
    float* counts = gsum + (size_t)BB * CC * DD;
    float* wcopy  = counts + BB * CC;           // 3 x 65536 fp32 aggr weights

    convert_all<<<2048 + 144 + 64 + 192, 256, 0, stream>>>(
        emb, BUF0, BUF1,
        (const float*)d_in[2], (const float*)d_in[3], (const float*)d_in[4],
        (const float*)d_in[5], (const float*)d_in[6], (const float*)d_in[7],
        (const float*)d_in[8], ffW1 + 256 * 256, (const float*)d_in[14], Wt,
        gsum, Wo1f, resW, ffW1, wcopy);
    // QKV0 (sel-merged)
    gemm_qkv<<<dim3(128, 4), 768, 0, stream>>>(
        BUF0, Wt, Wt + 65536, Wt + 2 * 65536, BUF2, BUF3, BUF4);
    attn_mfma<0><<<256, 1024, 0, stream>>>(BUF2, BUF3, BUF4, BUF5, nullptr);
    // X1 = gelu(attn0 @ Wo0) -> BUF0
    gemm64<1,0,0,0,0><<<dim3(128, 4), 256, 0, stream>>>(
        BUF5, Wt + 3 * 65536, BUF0, nullptr, nullptr, nullptr, nullptr, nullptr);
    // QKV1 (sel-merged)
    gemm_qkv<<<dim3(128, 4), 768, 0, stream>>>(
        BUF0, Wt + 4 * 65536, Wt + 5 * 65536, Wt + 6 * 65536, BUF2, BUF3, BUF4);
    // attn1: column sums only
    attn_mfma<1><<<256, 1024, 0, stream>>>(BUF2, BUF3, BUF4, nullptr, partial);
    aggr_v2<<<BB, 256, 0, stream>>>(
        partial, wcopy, wcopy + 65536, resb, wcopy + 2 * 65536, labels, tvec, counts);
    // H = gelu(gelu(e) @ W1btm + tvec + b1) -> BUF3
    gemm64<1,1,1,0,0><<<dim3(128, 4), 256, 0, stream>>>(
        BUF1, Wt + 7 * 65536, BUF3, nullptr, ffb1, tvec, nullptr, nullptr);
    // F = H @ W2 + b2 (fp32) + fused classsum atomics
    gemm64<0,1,0,1,1><<<dim3(128, 4), 256, 0, stream>>>(
        BUF3, Wt + 8 * 65536, nullptr, F, ffb2, nullptr, labels, gsum);
    out_kernel<<<dim3(128, BB), 256, 0, stream>>>(F, labels, gsum, counts, out);
}

// Round 9
// 191.876 us; speedup vs baseline: 1.0265x; 1.0265x over previous
//
#include <hip/hip_runtime.h>

#define BB 16
#define NN 512
#define DD 256
#define HH 8
#define CC 16

typedef unsigned short u16;
using short8 = __attribute__((ext_vector_type(8))) short;
using f32x4  = __attribute__((ext_vector_type(4))) float;

__device__ __forceinline__ float gelu_f(float x) {
    return 0.5f * x * (1.0f + erff(x * 0.70710678118654752f));
}
__device__ __forceinline__ u16 f2bf(float f) {
    unsigned int u = __float_as_uint(f);
    unsigned int r = u + 0x7FFFu + ((u >> 16) & 1u);
    return (u16)(r >> 16);
}
// packed f32x2 -> bf16x2 (RTNE, bit-identical to f2bf), 1 instr vs ~8
__device__ __forceinline__ unsigned cvtpk(float lo, float hi) {
    unsigned r;
    asm("v_cvt_pk_bf16_f32 %0, %1, %2" : "=v"(r) : "v"(lo), "v"(hi));
    return r;
}
// async global->LDS, 16B/lane; LDS dest = wave-uniform base + lane*16
__device__ __forceinline__ void gld16(const u16* g, const u16* l) {
    __builtin_amdgcn_global_load_lds(
        (const __attribute__((address_space(1))) unsigned int*)g,
        (__attribute__((address_space(3))) unsigned int*)l, 16, 0, 0);
}

// Q pre-scale: (1/sqrt(32)) * log2(e)  -> attention uses exp2
#define QSCALE 0.25505412f

// latency-unrolled matvec: 8 independent accumulator chains
__device__ __forceinline__ float mv256(const float* __restrict__ a,
                                       const float* __restrict__ W, int d)
{
    float acc[8] = {0.f, 0.f, 0.f, 0.f, 0.f, 0.f, 0.f, 0.f};
    for (int k = 0; k < 256; k += 8) {
#pragma unroll
        for (int j = 0; j < 8; ++j)
            acc[j] += a[k + j] * W[(size_t)(k + j) * 256 + d];
    }
    return ((acc[0] + acc[1]) + (acc[2] + acc[3])) + ((acc[4] + acc[5]) + (acc[6] + acc[7]));
}

// ---------------------------------------------------------------------------
// Generic 64x64-tile bf16 MFMA GEMM (BK=32, LDS staging). grid (128, 4).
// O = act(A @ Wt + bias + tvec[b]); token-major bf16 or fp32 out.
// CS=1: additionally reduce the fp32 tile per class and atomicAdd into gsum.
// ---------------------------------------------------------------------------
template<int ACT, int HAS_B, int HAS_T, int OUT_F32, int CS>
__global__ __launch_bounds__(256) void gemm64(
    const u16* __restrict__ A, const u16* __restrict__ W,
    u16* __restrict__ O, float* __restrict__ OF,
    const float* __restrict__ bias, const float* __restrict__ tvec,
    const int* __restrict__ labels, float* __restrict__ gsum)
{
    __shared__ __align__(16) u16 As[64 * 32];
    __shared__ __align__(16) u16 Bs[64 * 32];
    const int tid = threadIdx.x, wave = tid >> 6, lane = tid & 63;
    const int col = lane & 15, quad = lane >> 4;
    const int mbase = blockIdx.x * 64;
    const int nbase = blockIdx.y * 64;
    const int srow = lane >> 2, skk = (lane & 3) * 8;
    const int mh = (wave & 1) * 32, nh = (wave >> 1) * 32;

    f32x4 acc[2][2];
#pragma unroll
    for (int i = 0; i < 2; ++i)
#pragma unroll
        for (int j = 0; j < 2; ++j) acc[i][j] = (f32x4){0.f, 0.f, 0.f, 0.f};

    for (int k0 = 0; k0 < DD; k0 += 32) {
        gld16(A + (size_t)(mbase + wave * 16 + srow) * DD + k0 + skk, &As[wave * 512]);
        gld16(W + (size_t)(nbase + wave * 16 + srow) * DD + k0 + skk, &Bs[wave * 512]);
        __syncthreads();
        short8 af[2], bfr[2];
#pragma unroll
        for (int i = 0; i < 2; ++i) af[i]  = *(const short8*)&As[(mh + i * 16 + col) * 32 + quad * 8];
#pragma unroll
        for (int j = 0; j < 2; ++j) bfr[j] = *(const short8*)&Bs[(nh + j * 16 + col) * 32 + quad * 8];
#pragma unroll
        for (int i = 0; i < 2; ++i)
#pragma unroll
            for (int j = 0; j < 2; ++j)
                acc[i][j] = __builtin_amdgcn_mfma_f32_16x16x32_bf16(af[i], bfr[j], acc[i][j], 0, 0, 0);
        __syncthreads();
    }

    const int b = mbase >> 9;
    if constexpr (!CS) {
#pragma unroll
        for (int i = 0; i < 2; ++i) {
#pragma unroll
            for (int j = 0; j < 2; ++j) {
                const int ccol = nbase + nh + j * 16 + col;
                float vv[4];
#pragma unroll
                for (int r = 0; r < 4; ++r) {
                    float v = acc[i][j][r];
                    if (HAS_B) v += bias[ccol];
                    if (HAS_T) v += tvec[b * DD + ccol];
                    if (ACT)   v = gelu_f(v);
                    vv[r] = v;
                }
                const int crow0 = mbase + mh + i * 16 + quad * 4;
                if (OUT_F32) {
#pragma unroll
                    for (int r = 0; r < 4; ++r) OF[(size_t)(crow0 + r) * DD + ccol] = vv[r];
                } else {
                    const unsigned a = cvtpk(vv[0], vv[1]), c = cvtpk(vv[2], vv[3]);
                    O[(size_t)(crow0 + 0) * DD + ccol] = (u16)a;
                    O[(size_t)(crow0 + 1) * DD + ccol] = (u16)(a >> 16);
                    O[(size_t)(crow0 + 2) * DD + ccol] = (u16)c;
                    O[(size_t)(crow0 + 3) * DD + ccol] = (u16)(c >> 16);
                }
            }
        }
    } else {
        // fused classsum epilogue: write F + stage tile in LDS, per-class
        // reduce in-block, atomicAdd into gsum[b][c][d].
        __shared__ float Fs[64][65];
        __shared__ float gs[4][CC][64];
        __shared__ int lab2[64];
        if (tid < 64) lab2[tid] = labels[mbase + tid];
#pragma unroll
        for (int i = 0; i < 2; ++i) {
#pragma unroll
            for (int j = 0; j < 2; ++j) {
                const int lcol = nh + j * 16 + col;
                const int ccol = nbase + lcol;
#pragma unroll
                for (int r = 0; r < 4; ++r) {
                    const int lrow = mh + i * 16 + quad * 4 + r;
                    float v = acc[i][j][r];
                    if (HAS_B) v += bias[ccol];
                    if (HAS_T) v += tvec[b * DD + ccol];
                    if (ACT)   v = gelu_f(v);
                    OF[(size_t)(mbase + lrow) * DD + ccol] = v;
                    Fs[lrow][lcol] = v;
                }
            }
        }
        __syncthreads();
        float a[CC];
#pragma unroll
        for (int c = 0; c < CC; ++c) a[c] = 0.f;
#pragma unroll
        for (int n = 0; n < 16; ++n) {
            const float v = Fs[wave * 16 + n][lane];
            const int lb = lab2[wave * 16 + n];
#pragma unroll
            for (int c = 0; c < CC; ++c) a[c] += (lb == c) ? v : 0.f;
        }
#pragma unroll
        for (int c = 0; c < CC; ++c) gs[wave][c][lane] = a[c];
        __syncthreads();
#pragma unroll
        for (int i = 0; i < 4; ++i) {
            const int c = wave * 4 + i;
            atomicAdd(&gsum[((size_t)b * CC + c) * DD + nbase + lane],
                      gs[0][c][lane] + gs[1][c][lane] + gs[2][c][lane] + gs[3][c][lane]);
        }
    }
}

// ---------------------------------------------------------------------------
// QKV GEMM: 64x64 tiles, BK=32, LDS staging. grid (128, 12).
// sel = y>>2 picks Q/K/V; Q,K head-major [b,h,n,32] (Q scaled), V [b,h,32,n].
// R8's 12-wave sel-merge regressed (barrier convoy across 12 waves beat the
// ~25MB A-reuse saving) — keep the 4-wave sel-split form.
// ---------------------------------------------------------------------------
__global__ __launch_bounds__(256) void gemm_qkv(
    const u16* __restrict__ A,
    const u16* __restrict__ W0, const u16* __restrict__ W1, const u16* __restrict__ W2,
    u16* __restrict__ O0, u16* __restrict__ O1, u16* __restrict__ O2)
{
    __shared__ __align__(16) u16 As[64 * 32];
    __shared__ __align__(16) u16 Bs[64 * 32];
    const int tid = threadIdx.x, wave = tid >> 6, lane = tid & 63;
    const int col = lane & 15, quad = lane >> 4;
    const int mbase = blockIdx.x * 64;
    const int sel = blockIdx.y >> 2;
    const int nbase = (blockIdx.y & 3) * 64;
    const u16* W = (sel == 0) ? W0 : ((sel == 1) ? W1 : W2);
    u16* O = (sel == 0) ? O0 : ((sel == 1) ? O1 : O2);
    const int srow = lane >> 2, skk = (lane & 3) * 8;
    const int mh = (wave & 1) * 32, nh = (wave >> 1) * 32;

    f32x4 acc[2][2];
#pragma unroll
    for (int i = 0; i < 2; ++i)
#pragma unroll
        for (int j = 0; j < 2; ++j) acc[i][j] = (f32x4){0.f, 0.f, 0.f, 0.f};

    for (int k0 = 0; k0 < DD; k0 += 32) {
        gld16(A + (size_t)(mbase + wave * 16 + srow) * DD + k0 + skk, &As[wave * 512]);
        gld16(W + (size_t)(nbase + wave * 16 + srow) * DD + k0 + skk, &Bs[wave * 512]);
        __syncthreads();
        short8 af[2], bfr[2];
#pragma unroll
        for (int i = 0; i < 2; ++i) af[i]  = *(const short8*)&As[(mh + i * 16 + col) * 32 + quad * 8];
#pragma unroll
        for (int j = 0; j < 2; ++j) bfr[j] = *(const short8*)&Bs[(nh + j * 16 + col) * 32 + quad * 8];
#pragma unroll
        for (int i = 0; i < 2; ++i)
#pragma unroll
            for (int j = 0; j < 2; ++j)
                acc[i][j] = __builtin_amdgcn_mfma_f32_16x16x32_bf16(af[i], bfr[j], acc[i][j], 0, 0, 0);
        __syncthreads();
    }

    const int b = mbase >> 9;
#pragma unroll
    for (int i = 0; i < 2; ++i) {
#pragma unroll
        for (int j = 0; j < 2; ++j) {
            const int ccol = nbase + nh + j * 16 + col;
            const int tok0 = (mbase & 511) + mh + i * 16 + quad * 4;
            const int head = ccol >> 5, dk = ccol & 31;
            if (sel == 2) {
                uint2 pk;
                pk.x = cvtpk(acc[i][j][0], acc[i][j][1]);
                pk.y = cvtpk(acc[i][j][2], acc[i][j][3]);
                *(uint2*)&O[(((size_t)b * HH + head) * 32 + dk) * NN + tok0] = pk;
            } else {
                float vv[4];
#pragma unroll
                for (int r = 0; r < 4; ++r) {
                    float v = acc[i][j][r];
                    if (sel == 0) v *= QSCALE;
                    vv[r] = v;
                }
                const unsigned a = cvtpk(vv[0], vv[1]), c = cvtpk(vv[2], vv[3]);
                const size_t base = ((size_t)b * HH + head) * NN;
                O[(base + tok0 + 0) * 32 + dk] = (u16)a;
                O[(base + tok0 + 1) * 32 + dk] = (u16)(a >> 16);
                O[(base + tok0 + 2) * 32 + dk] = (u16)c;
                O[(base + tok0 + 3) * 32 + dk] = (u16)(c >> 16);
            }
        }
    }
}

// ---------------------------------------------------------------------------
// Flash MFMA attention, no-max softmax (pre-scaled by log2e/sqrt(dk), exp2).
// R7 config (measured best): 128 q-rows per block, 8 waves, grid 512.
// V staged 4x per (b,h); R8's 256-row/16-wave widening regressed (tail +
// epilogue span beat the remaining staging savings). Per-wave main loop:
// R2 structure + cvtpk + setprio.
// grid 512: gid = qb*128 + (b*8+h); COLSUM partial is [128 bh][4 qb][32].
// ---------------------------------------------------------------------------
template<int COLSUM>
__global__ __launch_bounds__(512) void attn_mfma(
    const u16* __restrict__ Qh, const u16* __restrict__ Kh,
    const u16* __restrict__ VT, u16* __restrict__ O,
    float* __restrict__ partial)
{
    __shared__ __align__(16) u16 Vt[32 * 520];
    __shared__ __align__(16) u16 Pc[8][16 * 32];
    __shared__ float cs[8][32];
    const int tid = threadIdx.x, wave = tid >> 6, lane = tid & 63;
    const int col = lane & 15, quad = lane >> 4;
    const int gid = blockIdx.x;
    const int qb = gid >> 7, bh = gid & 127;
    const int q0 = qb * 128 + wave * 16;

    const u16* vsrc = VT + (size_t)bh * 32 * NN;
#pragma unroll
    for (int i = 0; i < 4; ++i) {
        const int row = wave + i * 8;
        gld16(vsrc + (size_t)row * NN + lane * 8, &Vt[row * 520]);
    }
    const short8 aq = *(const short8*)(Qh + ((size_t)bh * NN + q0 + col) * 32 + quad * 8);
    __syncthreads();

    const u16* ksrc = Kh + (size_t)bh * NN * 32;
    float l[4] = {0.f, 0.f, 0.f, 0.f};
    f32x4 oacc[2];
    oacc[0] = (f32x4){0.f, 0.f, 0.f, 0.f};
    oacc[1] = (f32x4){0.f, 0.f, 0.f, 0.f};

    // K prefetch: two fragments in flight one g-iteration ahead
    short8 bkp[2];
#pragma unroll
    for (int k2 = 0; k2 < 2; ++k2)
        bkp[k2] = *(const short8*)(ksrc + (size_t)(k2 * 16 + col) * 32 + quad * 8);

    for (int g = 0; g < 16; ++g) {
        short8 bk0 = bkp[0], bk1 = bkp[1];
        if (g < 15) {
#pragma unroll
            for (int k2 = 0; k2 < 2; ++k2)
                bkp[k2] = *(const short8*)(ksrc + (size_t)((g * 2 + 2 + k2) * 16 + col) * 32 + quad * 8);
        }
        const f32x4 z = {0.f, 0.f, 0.f, 0.f};
        __builtin_amdgcn_s_setprio(1);
        const f32x4 s0 = __builtin_amdgcn_mfma_f32_16x16x32_bf16(aq, bk0, z, 0, 0, 0);
        const f32x4 s1 = __builtin_amdgcn_mfma_f32_16x16x32_bf16(aq, bk1, z, 0, 0, 0);
        __builtin_amdgcn_s_setprio(0);
#pragma unroll
        for (int k2 = 0; k2 < 2; ++k2) {
            const f32x4 s = k2 ? s1 : s0;
            const float p0 = exp2f(s[0]), p1 = exp2f(s[1]);
            const float p2 = exp2f(s[2]), p3 = exp2f(s[3]);
            l[0] += p0; l[1] += p1; l[2] += p2; l[3] += p3;
            const unsigned pa = cvtpk(p0, p1), pb = cvtpk(p2, p3);
            // swizzled unit index: u = k2*2 + (col>>3), u' = u ^ quad
            const int ubase = (((k2 * 2 + (col >> 3)) ^ quad) << 3) + (col & 7);
            u16* pcb = &Pc[wave][0];
            pcb[(quad * 4 + 0) * 32 + ubase] = (u16)pa;
            pcb[(quad * 4 + 1) * 32 + ubase] = (u16)(pa >> 16);
            pcb[(quad * 4 + 2) * 32 + ubase] = (u16)pb;
            pcb[(quad * 4 + 3) * 32 + ubase] = (u16)(pb >> 16);
        }
        const short8 ap = *(const short8*)&Pc[wave][col * 32 + ((quad ^ (col >> 2)) << 3)];
        __builtin_amdgcn_s_setprio(1);
#pragma unroll
        for (int nt = 0; nt < 2; ++nt) {
            const short8 bv = *(const short8*)&Vt[(nt * 16 + col) * 520 + g * 32 + quad * 8];
            oacc[nt] = __builtin_amdgcn_mfma_f32_16x16x32_bf16(ap, bv, oacc[nt], 0, 0, 0);
        }
        __builtin_amdgcn_s_setprio(0);
    }
#pragma unroll
    for (int r = 0; r < 4; ++r) {
        l[r] += __shfl_xor(l[r], 1, 64);
        l[r] += __shfl_xor(l[r], 2, 64);
        l[r] += __shfl_xor(l[r], 4, 64);
        l[r] += __shfl_xor(l[r], 8, 64);
    }
    float invl[4];
#pragma unroll
    for (int r = 0; r < 4; ++r) invl[r] = 1.0f / l[r];
    if (COLSUM) {
        float sv[2] = {0.f, 0.f};
#pragma unroll
        for (int nt = 0; nt < 2; ++nt) {
#pragma unroll
            for (int r = 0; r < 4; ++r) sv[nt] += oacc[nt][r] * invl[r];
            sv[nt] += __shfl_xor(sv[nt], 16, 64);
            sv[nt] += __shfl_xor(sv[nt], 32, 64);
        }
        if (lane < 16) { cs[wave][col] = sv[0]; cs[wave][16 + col] = sv[1]; }
        __syncthreads();
        if (tid < 32)
            partial[(size_t)(bh * 4 + qb) * 32 + tid] =
                cs[0][tid] + cs[1][tid] + cs[2][tid] + cs[3][tid] +
                cs[4][tid] + cs[5][tid] + cs[6][tid] + cs[7][tid];
    } else {
        const int b = bh >> 3, h = bh & 7;
        u16* obase = O + ((size_t)b * NN) * DD + h * 32;
#pragma unroll
        for (int nt = 0; nt < 2; ++nt) {
            const unsigned a = cvtpk(oacc[nt][0] * invl[0], oacc[nt][1] * invl[1]);
            const unsigned c = cvtpk(oacc[nt][2] * invl[2], oacc[nt][3] * invl[3]);
            const size_t rb = (size_t)(q0 + quad * 4);
            obase[(rb + 0) * DD + nt * 16 + col] = (u16)a;
            obase[(rb + 1) * DD + nt * 16 + col] = (u16)(a >> 16);
            obase[(rb + 2) * DD + nt * 16 + col] = (u16)c;
            obase[(rb + 3) * DD + nt * 16 + col] = (u16)(c >> 16);
        }
    }
}

// ---------------------------------------------------------------------------
// convert + weight transposes + zero gsum + stage aggr's fp32 weights into
// the workspace (guards against cold-HBM outliers on aggr's weight reads).
// ---------------------------------------------------------------------------
__global__ __launch_bounds__(256) void convert_all(
    const float* __restrict__ e, u16* __restrict__ E, u16* __restrict__ G,
    const float* s0, const float* s1, const float* s2, const float* s3,
    const float* s4, const float* s5, const float* s6, const float* s7,
    const float* s8, u16* __restrict__ Wt, float* __restrict__ gsum,
    const float* __restrict__ c0, const float* __restrict__ c1,
    const float* __restrict__ c2, float* __restrict__ wc)
{
    const int bx = blockIdx.x;
    if (bx < 2048) {
        const size_t i = ((size_t)bx * 256 + threadIdx.x) * 4;
        const float4 v = *(const float4*)(e + i);
        uint2 ev, gv;
        ev.x = cvtpk(v.x, v.y); ev.y = cvtpk(v.z, v.w);
        gv.x = cvtpk(gelu_f(v.x), gelu_f(v.y));
        gv.y = cvtpk(gelu_f(v.z), gelu_f(v.w));
        *(uint2*)(E + i) = ev;
        *(uint2*)(G + i) = gv;
    } else if (bx < 2192) {
        const int w = bx - 2048;
        const int my = w >> 4, kb = (w & 15) * 16;
        const int n = threadIdx.x;
        const float* S;
        switch (my) {
            case 0: S = s0; break; case 1: S = s1; break; case 2: S = s2; break;
            case 3: S = s3; break; case 4: S = s4; break; case 5: S = s5; break;
            case 6: S = s6; break; case 7: S = s7; break; default: S = s8; break;
        }
        u16* Dst = Wt + (size_t)my * 65536;
        for (int r = 0; r < 16; ++r) {
            const int k = kb + r;
            Dst[(size_t)n * 256 + k] = f2bf(S[(size_t)k * 256 + n]);
        }
    } else if (bx < 2256) {
        const int z = bx - 2192;   // 64 blocks zero gsum (65536 floats)
        const float4 zz = {0.f, 0.f, 0.f, 0.f};
        *(float4*)(gsum + (size_t)z * 1024 + threadIdx.x * 4) = zz;
    } else {
        // 192 blocks: bit-exact fp32 copy of Wo1 / resW / ffW1-top (256KB each)
        const int w = bx - 2256;
        const int m = w >> 6;              // 0..2
        const float* src = (m == 0) ? c0 : ((m == 1) ? c1 : c2);
        const size_t off = (size_t)(w & 63) * 1024 + threadIdx.x * 4;
        *(float4*)(wc + (size_t)m * 65536 + off) = *(const float4*)(src + off);
    }
}

// aggr: m1=mean(attn1 colsums); a1=gelu(m1@Wo1); a2=gelu(a1@resW+resb);
// tvec=a2@ffW1[0:256]; also counts histogram. grid BB.
// partial is [128 bh][4 qb][32] (128-q attn blocks).
__global__ __launch_bounds__(256) void aggr_v2(
    const float* __restrict__ partial, const float* __restrict__ Wo1f,
    const float* __restrict__ resW, const float* __restrict__ resb,
    const float* __restrict__ W1, const int* __restrict__ labels,
    float* __restrict__ tvec, float* __restrict__ counts)
{
    const int b = blockIdx.x, d = threadIdx.x;
    __shared__ float a0[256], a1[256], a2[256];
    __shared__ int hist[CC];
    if (d < CC) hist[d] = 0;
    const int h = d >> 5, d32 = d & 31;
    float s = 0.f;
#pragma unroll
    for (int qb = 0; qb < 4; ++qb)
        s += partial[(size_t)(((b * 8 + h) * 4) + qb) * 32 + d32];
    a0[d] = s * (1.0f / NN);
    __syncthreads();
    atomicAdd(&hist[labels[b * NN + d]], 1);
    atomicAdd(&hist[labels[b * NN + 256 + d]], 1);
    a1[d] = gelu_f(mv256(a0, Wo1f, d));
    __syncthreads();
    a2[d] = gelu_f(mv256(a1, resW, d) + resb[d]);
    __syncthreads();
    tvec[b * 256 + d] = mv256(a2, W1, d);
    if (d < CC) counts[b * CC + d] = (float)hist[d];
}

__global__ __launch_bounds__(256) void out_kernel(
    const float* __restrict__ F, const int* __restrict__ labels,
    const float* __restrict__ g, const float* __restrict__ counts,
    float* __restrict__ out)
{
    const int b = blockIdx.y;
    const int wave = threadIdx.x >> 6, lane = threadIdx.x & 63;
    const int n = blockIdx.x * 4 + wave;
    const float* fn = F + ((size_t)b * NN + n) * DD;
    const float* gb = g + (size_t)b * CC * DD;
    float fv[4];
#pragma unroll
    for (int i = 0; i < 4; ++i) fv[i] = fn[lane * 4 + i];
    float selfdot = 0.f;
#pragma unroll
    for (int i = 0; i < 4; ++i) selfdot += fv[i] * fv[i];
    float accs[CC];
#pragma unroll
    for (int c = 0; c < CC; ++c) {
        float sacc = 0.f;
#pragma unroll
        for (int i = 0; i < 4; ++i) sacc += fv[i] * gb[c * DD + lane * 4 + i];
        accs[c] = sacc;
    }
    for (int off = 32; off; off >>= 1) {
        selfdot += __shfl_xor(selfdot, off, 64);
#pragma unroll
        for (int c = 0; c < CC; ++c) accs[c] += __shfl_xor(accs[c], off, 64);
    }
    if (lane < CC) {
        const int c = lane;
        const int same = (labels[b * NN + n] == c) ? 1 : 0;
        const float num = accs[c] - (same ? selfdot : 0.f);
        const float den = counts[b * CC + c] - (float)same;
        out[((size_t)b * NN + n) * CC + c] = num / den;
    }
}

// ---------------------------------------------------------------------------
extern "C" void kernel_launch(void* const* d_in, const int* in_sizes, int n_in,
                              void* d_out, int out_size, void* d_ws, size_t ws_size,
                              hipStream_t stream)
{
    const float* emb    = (const float*)d_in[0];
    const int*   labels = (const int*)  d_in[1];
    const float* Wo1f = (const float*)d_in[9];
    const float* resW = (const float*)d_in[10];
    const float* resb = (const float*)d_in[11];
    const float* ffW1 = (const float*)d_in[12];
    const float* ffb1 = (const float*)d_in[13];
    const float* ffb2 = (const float*)d_in[15];
    float* out = (float*)d_out;

    const size_t SBE = (size_t)BB * NN * DD;
    u16* BUF0 = (u16*)d_ws;          // E_bf, later X1
    u16* BUF1 = BUF0 + SBE;          // gelu(emb) bf16
    u16* BUF2 = BUF1 + SBE;          // Qh [b,h,n,32]
    u16* BUF3 = BUF2 + SBE;          // Kh, later H
    u16* BUF4 = BUF3 + SBE;          // VT [b,h,32,n]
    u16* BUF5 = BUF4 + SBE;          // attn0 out (token-major)
    u16* Wt   = BUF5 + SBE;          // 9 x [256n x 256k] bf16 transposed
    float* F      = (float*)(Wt + 9 * 65536);   // [8192x256] fp32 features
    float* tvec   = F + SBE;
    float* partial= tvec + BB * 256;            // [128 bh][4 qb][32]
    float* gsum   = partial + 128 * 8 * 32;
    float* counts = gsum + (size_t)BB * CC * DD;
    float* wcopy  = counts + BB * CC;           // 3 x 65536 fp32 aggr weights

    convert_all<<<2048 + 144 + 64 + 192, 256, 0, stream>>>(
        emb, BUF0, BUF1,
        (const float*)d_in[2], (const float*)d_in[3], (const float*)d_in[4],
        (const float*)d_in[5], (const float*)d_in[6], (const float*)d_in[7],
        (const float*)d_in[8], ffW1 + 256 * 256, (const float*)d_in[14], Wt,
        gsum, Wo1f, resW, ffW1, wcopy);
    // QKV0
    gemm_qkv<<<dim3(128, 12), 256, 0, stream>>>(
        BUF0, Wt, Wt + 65536, Wt + 2 * 65536, BUF2, BUF3, BUF4);
    attn_mfma<0><<<512, 512, 0, stream>>>(BUF2, BUF3, BUF4, BUF5, nullptr);
    // X1 = gelu(attn0 @ Wo0) -> BUF0
    gemm64<1,0,0,0,0><<<dim3(128, 4), 256, 0, stream>>>(
        BUF5, Wt + 3 * 65536, BUF0, nullptr, nullptr, nullptr, nullptr, nullptr);
    // QKV1
    gemm_qkv<<<dim3(128, 12), 256, 0, stream>>>(
        BUF0, Wt + 4 * 65536, Wt + 5 * 65536, Wt + 6 * 65536, BUF2, BUF3, BUF4);
    // attn1: column sums only
    attn_mfma<1><<<512, 512, 0, stream>>>(BUF2, BUF3, BUF4, nullptr, partial);
    aggr_v2<<<BB, 256, 0, stream>>>(
        partial, wcopy, wcopy + 65536, resb, wcopy + 2 * 65536, labels, tvec, counts);
    // H = gelu(gelu(e) @ W1btm + tvec + b1) -> BUF3
    gemm64<1,1,1,0,0><<<dim3(128, 4), 256, 0, stream>>>(
        BUF1, Wt + 7 * 65536, BUF3, nullptr, ffb1, tvec, nullptr, nullptr);
    // F = H @ W2 + b2 (fp32) + fused classsum atomics
    gemm64<0,1,0,1,1><<<dim3(128, 4), 256, 0, stream>>>(
        BUF3, Wt + 8 * 65536, nullptr, F, ffb2, nullptr, labels, gsum);
    out_kernel<<<dim3(128, BB), 256, 0, stream>>>(F, labels, gsum, counts, out);
}